// Round 13
// baseline (260.833 us; speedup 1.0000x reference)
//
#include <hip/hip_runtime.h>
#include <math.h>

// Problem constants: N=32768 nodes, E=262144 edges, HID=64, HEADS=4
#define HIDDEN 64
#define HEADS 4
#define HC 256   // HEADS * HIDDEN
#define CAP 64   // bucket capacity per dst node (Poisson(8): P(deg>64) ~ 0)

typedef __attribute__((ext_vector_type(8))) short short8;   // 8 bf16 (4 VGPRs)
typedef __attribute__((ext_vector_type(4))) float f32x4;    // MFMA acc

__device__ __forceinline__ unsigned short f2bf(float f) {
    unsigned int u = __float_as_uint(f);
    u += 0x7fffu + ((u >> 16) & 1u);   // round-to-nearest-even
    return (unsigned short)(u >> 16);
}

// ---------------- prep ----------------
// b<2048: zb = bf16(h).  [2048,2112): wtm1/wtm2[c*256 + h*64+d] = bf16(0.25*W[d][h*64+c])
// (B^T layout for the out-GEMM, K=h*64+d, 0.25 head-mean folded in).
// 2112: wr (edge-attn reduction, both layers).  [2113,2117): wvec = W_h @ a_{src,dst}
// per head (layer, sd).  [2117,2245): zero counts.
__global__ __launch_bounds__(256) void k_prep(const float* __restrict__ h,
                                              const float* __restrict__ W1f,
                                              const float* __restrict__ W2f,
                                              const float* __restrict__ We1,
                                              const float* __restrict__ at1,
                                              const float* __restrict__ We2,
                                              const float* __restrict__ at2,
                                              const float* __restrict__ as1,
                                              const float* __restrict__ ad1,
                                              const float* __restrict__ as2,
                                              const float* __restrict__ ad2,
                                              ushort* __restrict__ zb,
                                              ushort* __restrict__ wtm1,
                                              ushort* __restrict__ wtm2,
                                              float* __restrict__ wr,
                                              float* __restrict__ wvec,
                                              int* __restrict__ counts) {
    int t = threadIdx.x, b = blockIdx.x;
    if (b < 2048) {
        int i = b * 256 + t;
        float4 v = ((const float4*)h)[i];
        ushort4 o;
        o.x = f2bf(v.x); o.y = f2bf(v.y); o.z = f2bf(v.z); o.w = f2bf(v.w);
        ((ushort4*)zb)[i] = o;
    } else if (b < 2112) {
        int j = (b - 2048) * 256 + t;   // 0..16383 ; j = c*256 + (h*64+d)
        int c = j >> 8, k = j & 255;
        int hh = k >> 6, d = k & 63;
        wtm1[j] = f2bf(0.25f * W1f[d * HC + hh * HIDDEN + c]);
        wtm2[j] = f2bf(0.25f * W2f[d * HC + hh * HIDDEN + c]);
    } else if (b == 2112) {
        int wv = t >> 6, lane = t & 63;
#pragma unroll
        for (int it = 0; it < 6; ++it) {
            int comb = wv + it * 4;          // 0..23
            int layer = comb / 12;
            int dh = comb % 12;
            int d = dh >> 2, hh = dh & 3;
            const float* We = layer ? We2 : We1;
            const float* at = layer ? at2 : at1;
            float v = We[d * HC + hh * HIDDEN + lane] * at[hh * HIDDEN + lane];
            for (int o = 32; o > 0; o >>= 1) v += __shfl_down(v, o);
            if (lane == 0) wr[layer * 16 + d * HEADS + hh] = v;
        }
    } else if (b < 2117) {
        // wvec[layer][sd][h][d] = sum_c W[d][h*64+c] * a_{sd}[h][c]
        int blk = b - 2113;               // 0..3
        int layer = blk >> 1, sd = blk & 1;
        const float* W = layer ? W2f : W1f;
        const float* at = layer ? (sd ? ad2 : as2) : (sd ? ad1 : as1);
        int hh = t >> 6, d = t & 63;      // wave = head, lane = d
        float v = 0.f;
        for (int c = 0; c < 64; ++c)
            v += W[d * HC + hh * HIDDEN + c] * at[hh * HIDDEN + c];
        wvec[layer * 512 + sd * 256 + hh * 64 + d] = v;
    } else {
        counts[(b - 2117) * 256 + t] = 0;
    }
}

// One-pass bucket CSR: slot = dst*CAP + atomic count. Writes src index and
// both layers' edge-attention contributions directly into dst-grouped slots.
__global__ __launch_bounds__(256) void k_bucket(const int* __restrict__ dst,
                                                const int* __restrict__ src,
                                                const float* __restrict__ ea,
                                                const float* __restrict__ wr,
                                                int* __restrict__ counts,
                                                int* __restrict__ sb,
                                                float* __restrict__ a1b,
                                                float* __restrict__ a2b, int E) {
    int e = blockIdx.x * blockDim.x + threadIdx.x;
    if (e >= E) return;
    int d = dst[e];
    int c = atomicAdd(&counts[d], 1);
    if (c >= CAP) return;   // statistically impossible; memory-safety clamp
    size_t slot = (size_t)d * CAP + c;
    sb[slot] = src[e];
    float a0 = ea[e * 3 + 0];
    float a1 = ea[e * 3 + 1];
    float a2 = ea[e * 3 + 2];
    float o1[4], o2[4];
#pragma unroll
    for (int hh = 0; hh < 4; ++hh) {
        o1[hh] = a0 * wr[hh] + a1 * wr[4 + hh] + a2 * wr[8 + hh];
        o2[hh] = a0 * wr[16 + hh] + a1 * wr[20 + hh] + a2 * wr[24 + hh];
    }
    *(float4*)&a1b[slot * 4] = make_float4(o1[0], o1[1], o1[2], o1[3]);
    *(float4*)&a2b[slot * 4] = make_float4(o2[0], o2[1], o2[2], o2[3]);
}

// Per-node alpha: as[n,h] = z[n]·wvec_src[h], ad[n,h] = z[n]·wvec_dst[h].
// One thread per node (z row = 128 B bf16; wvec is L1-resident 2 KB).
__global__ __launch_bounds__(256) void k_alpha(const ushort* __restrict__ zb,
                                               const float* __restrict__ wv,
                                               float* __restrict__ as_,
                                               float* __restrict__ adv, int N) {
    int n = blockIdx.x * 256 + threadIdx.x;
    if (n >= N) return;
    const uint4* zr = (const uint4*)(zb + (size_t)n * 64);
    float s[4] = {0, 0, 0, 0}, d[4] = {0, 0, 0, 0};
#pragma unroll
    for (int j = 0; j < 8; ++j) {
        uint4 z4 = zr[j];
        unsigned u[4] = {z4.x, z4.y, z4.z, z4.w};
#pragma unroll
        for (int k = 0; k < 4; ++k) {
            float lo = __uint_as_float(u[k] << 16);
            float hi = __uint_as_float(u[k] & 0xffff0000u);
            int c = j * 8 + 2 * k;
#pragma unroll
            for (int hh = 0; hh < 4; ++hh) {
                s[hh] += lo * wv[hh * 64 + c] + hi * wv[hh * 64 + c + 1];
                d[hh] += lo * wv[256 + hh * 64 + c] + hi * wv[256 + hh * 64 + c + 1];
            }
        }
    }
    *(float4*)&as_[n * 4] = make_float4(s[0], s[1], s[2], s[3]);
    *(float4*)&adv[n * 4] = make_float4(d[0], d[1], d[2], d[3]);
}

// z-space aggregate: zagg[n,h,:] = (sum_e w_{e,h} z[s_e]) / (sum_e w_{e,h}).
// Wave per node (grid-stride). lane = e*8+g: e = edge slot (8), g = 8-channel
// group of the 64-dim z row. Gather is 8 random 128 B rows per chunk, from a
// 4 MB table (fits per-XCD L2).
__global__ __launch_bounds__(256) void k_aggz(
        const ushort* __restrict__ zb, const float* __restrict__ aes,
        const int* __restrict__ sb, const int* __restrict__ counts,
        const float* __restrict__ as_, const float* __restrict__ ad_,
        ushort* __restrict__ zagg, int N) {
    int lane = threadIdx.x & 63;
    int e = lane >> 3, g = lane & 7;
    int wid = blockIdx.x * 4 + (threadIdx.x >> 6);
    int nwaves = gridDim.x * 4;

    for (int n = wid; n < N; n += nwaves) {
        int deg = counts[n];
        if (deg > CAP) deg = CAP;
        int base = n * CAP;
        float4 adv4 = *(const float4*)&ad_[n * 4];

        float acc[4][8];
        float ssum[4] = {0.f, 0.f, 0.f, 0.f};
#pragma unroll
        for (int hh = 0; hh < 4; ++hh)
#pragma unroll
            for (int k = 0; k < 8; ++k) acc[hh][k] = 0.f;

        for (int cs = 0; cs < deg; cs += 8) {
            int idx = cs + e;
            int s = 0;
            float w[4] = {0.f, 0.f, 0.f, 0.f};
            if (idx < deg) {
                s = sb[base + idx];
                float4 av = *(const float4*)&as_[s * 4];
                float4 cv = *(const float4*)&aes[(size_t)(base + idx) * 4];
                float lg;
                lg = av.x + adv4.x + cv.x; lg = (lg >= 0.f) ? lg : 0.2f * lg; w[0] = __expf(lg);
                lg = av.y + adv4.y + cv.y; lg = (lg >= 0.f) ? lg : 0.2f * lg; w[1] = __expf(lg);
                lg = av.z + adv4.z + cv.z; lg = (lg >= 0.f) ? lg : 0.2f * lg; w[2] = __expf(lg);
                lg = av.w + adv4.w + cv.w; lg = (lg >= 0.f) ? lg : 0.2f * lg; w[3] = __expf(lg);
            }
#pragma unroll
            for (int hh = 0; hh < 4; ++hh) ssum[hh] += w[hh];
            uint4 raw = *(const uint4*)&zb[(size_t)s * 64 + g * 8];
            unsigned u[4] = {raw.x, raw.y, raw.z, raw.w};
#pragma unroll
            for (int k = 0; k < 4; ++k) {
                float lo = __uint_as_float(u[k] << 16);
                float hi = __uint_as_float(u[k] & 0xffff0000u);
#pragma unroll
                for (int hh = 0; hh < 4; ++hh) {
                    acc[hh][2 * k + 0] += w[hh] * lo;
                    acc[hh][2 * k + 1] += w[hh] * hi;
                }
            }
        }
        // reduce over the 8 edge slots (xor bits 3,4,5)
#pragma unroll
        for (int o = 8; o < 64; o <<= 1) {
#pragma unroll
            for (int hh = 0; hh < 4; ++hh) {
                ssum[hh] += __shfl_xor(ssum[hh], o);
#pragma unroll
                for (int k = 0; k < 8; ++k)
                    acc[hh][k] += __shfl_xor(acc[hh][k], o);
            }
        }
        if (e == 0) {
#pragma unroll
            for (int hh = 0; hh < 4; ++hh) {
                float winv = 1.f / (ssum[hh] + 1e-16f);
                uint4 pk;
                pk.x = (unsigned)f2bf(acc[hh][0] * winv) | ((unsigned)f2bf(acc[hh][1] * winv) << 16);
                pk.y = (unsigned)f2bf(acc[hh][2] * winv) | ((unsigned)f2bf(acc[hh][3] * winv) << 16);
                pk.z = (unsigned)f2bf(acc[hh][4] * winv) | ((unsigned)f2bf(acc[hh][5] * winv) << 16);
                pk.w = (unsigned)f2bf(acc[hh][6] * winv) | ((unsigned)f2bf(acc[hh][7] * winv) << 16);
                *(uint4*)&zagg[(size_t)n * HC + hh * 64 + g * 8] = pk;
            }
        }
    }
}

// Out-GEMM: y[n,c] = SiLU(LN( zagg[n,:] @ wtm[:,c] + bias[c] )) — K=256,
// 0.25 head-mean folded into wtm. mfma_f32_16x16x32_bf16; wave = 16 rows,
// 32 MFMAs; LN over the 64 cols via quad-local xor shuffles.
__global__ __launch_bounds__(256) void k_out(const ushort* __restrict__ zagg,
                                             const ushort* __restrict__ wtm,
                                             const float* __restrict__ bias,
                                             const float* __restrict__ lng,
                                             const float* __restrict__ lnb,
                                             float* __restrict__ outf,
                                             ushort* __restrict__ outb) {
    int wave = threadIdx.x >> 6, lane = threadIdx.x & 63;
    int q = lane & 15, quad = lane >> 4;
    int row0 = blockIdx.x * 64 + wave * 16;

    const ushort* arow = zagg + (size_t)(row0 + q) * HC + quad * 8;
    short8 a[8];
#pragma unroll
    for (int ks = 0; ks < 8; ++ks) a[ks] = *(const short8*)(arow + ks * 32);

    f32x4 acc[4];
#pragma unroll
    for (int nt = 0; nt < 4; ++nt) {
        acc[nt] = (f32x4){0.f, 0.f, 0.f, 0.f};
        const ushort* brow = wtm + (size_t)(nt * 16 + q) * HC + quad * 8;
#pragma unroll
        for (int ks = 0; ks < 8; ++ks) {
            short8 bfr = *(const short8*)(brow + ks * 32);
            acc[nt] = __builtin_amdgcn_mfma_f32_16x16x32_bf16(a[ks], bfr, acc[nt], 0, 0, 0);
        }
    }

    // epilogue: +bias, LN over 64 cols (4 in-lane tiles x 16 q-lanes), SiLU
    float bs[4], gm[4], bt[4];
#pragma unroll
    for (int nt = 0; nt < 4; ++nt) {
        bs[nt] = bias[nt * 16 + q];
        gm[nt] = lng[nt * 16 + q];
        bt[nt] = lnb[nt * 16 + q];
    }
    float u[4][4];
#pragma unroll
    for (int nt = 0; nt < 4; ++nt)
#pragma unroll
        for (int r = 0; r < 4; ++r) u[nt][r] = acc[nt][r] + bs[nt];

    float s1[4];
#pragma unroll
    for (int r = 0; r < 4; ++r) s1[r] = u[0][r] + u[1][r] + u[2][r] + u[3][r];
#pragma unroll
    for (int o = 1; o < 16; o <<= 1)
#pragma unroll
        for (int r = 0; r < 4; ++r) s1[r] += __shfl_xor(s1[r], o);
    float mu[4];
#pragma unroll
    for (int r = 0; r < 4; ++r) mu[r] = s1[r] * (1.f / 64.f);

    float s2[4];
#pragma unroll
    for (int r = 0; r < 4; ++r) {
        s2[r] = 0.f;
#pragma unroll
        for (int nt = 0; nt < 4; ++nt) {
            float dd = u[nt][r] - mu[r];
            s2[r] += dd * dd;
        }
    }
#pragma unroll
    for (int o = 1; o < 16; o <<= 1)
#pragma unroll
        for (int r = 0; r < 4; ++r) s2[r] += __shfl_xor(s2[r], o);

#pragma unroll
    for (int r = 0; r < 4; ++r) {
        float rstd = rsqrtf(s2[r] * (1.f / 64.f) + 1e-5f);
        int row = row0 + quad * 4 + r;
#pragma unroll
        for (int nt = 0; nt < 4; ++nt) {
            float y = (u[nt][r] - mu[r]) * rstd * gm[nt] + bt[nt];
            float res = y / (1.f + __expf(-y));
            int col = nt * 16 + q;
            if (outb) outb[(size_t)row * HIDDEN + col] = f2bf(res);
            else outf[(size_t)row * HIDDEN + col] = res;
        }
    }
}

// ---------------- launch ----------------

extern "C" void kernel_launch(void* const* d_in, const int* in_sizes, int n_in,
                              void* d_out, int out_size, void* d_ws, size_t ws_size,
                              hipStream_t stream) {
    const float* h   = (const float*)d_in[1];
    const int*   ei  = (const int*)d_in[2];
    const float* ea  = (const float*)d_in[3];
    const float* W1  = (const float*)d_in[4];
    const float* We1 = (const float*)d_in[5];
    const float* as1 = (const float*)d_in[6];
    const float* ad1 = (const float*)d_in[7];
    const float* ae1 = (const float*)d_in[8];
    const float* b1  = (const float*)d_in[9];
    const float* lg1 = (const float*)d_in[10];
    const float* lb1 = (const float*)d_in[11];
    const float* W2  = (const float*)d_in[12];
    const float* We2 = (const float*)d_in[13];
    const float* as2 = (const float*)d_in[14];
    const float* ad2 = (const float*)d_in[15];
    const float* ae2 = (const float*)d_in[16];
    const float* b2  = (const float*)d_in[17];
    const float* lg2 = (const float*)d_in[18];
    const float* lb2 = (const float*)d_in[19];

    const int N = in_sizes[1] / HIDDEN;   // 32768
    const int E = in_sizes[2] / 2;        // 262144
    const int* srcp = ei;
    const int* dstp = ei + E;

    // workspace layout (all regions fully written before read)
    char* w = (char*)d_ws;
    ushort* zb    = (ushort*)w; w += (size_t)N * HIDDEN * 2;    // 4 MB
    ushort* zagg  = (ushort*)w; w += (size_t)N * HC * 2;        // 16.75 MB
    float* as_    = (float*)w;  w += (size_t)N * HEADS * 4;
    float* adv    = (float*)w;  w += (size_t)N * HEADS * 4;
    ushort* wtm1  = (ushort*)w; w += 16384 * 2;
    ushort* wtm2  = (ushort*)w; w += 16384 * 2;
    float* wr     = (float*)w;  w += 128;
    float* wvec   = (float*)w;  w += 1024 * 4;
    int* counts   = (int*)w;    w += (size_t)N * 4;
    int* sb       = (int*)w;    w += (size_t)N * CAP * 4;       // 8 MB
    float* a1b    = (float*)w;  w += (size_t)N * CAP * 4 * 4;   // 32 MB
    float* a2b    = (float*)w;  w += (size_t)N * CAP * 4 * 4;   // 32 MB

    // prep (zb, wtm, wr, wvec, zero counts) -> one-pass bucket CSR
    k_prep<<<2245, 256, 0, stream>>>(h, W1, W2, We1, ae1, We2, ae2,
                                     as1, ad1, as2, ad2,
                                     zb, wtm1, wtm2, wr, wvec, counts);
    k_bucket<<<(E + 255) / 256, 256, 0, stream>>>(dstp, srcp, ea, wr, counts,
                                                  sb, a1b, a2b, E);

    // layer 1
    k_alpha<<<N / 256, 256, 0, stream>>>(zb, wvec, as_, adv, N);
    k_aggz<<<4096, 256, 0, stream>>>(zb, a1b, sb, counts, as_, adv, zagg, N);
    k_out<<<N / 64, 256, 0, stream>>>(zagg, wtm1, b1, lg1, lb1, nullptr, zb);
    // layer 2 (zb now holds z2)
    k_alpha<<<N / 256, 256, 0, stream>>>(zb, wvec + 512, as_, adv, N);
    k_aggz<<<4096, 256, 0, stream>>>(zb, a2b, sb, counts, as_, adv, zagg, N);
    k_out<<<N / 64, 256, 0, stream>>>(zagg, wtm2, b2, lg2, lb2, (float*)d_out, nullptr);
}

// Round 14
// 222.020 us; speedup vs baseline: 1.1748x; 1.1748x over previous
//
#include <hip/hip_runtime.h>
#include <math.h>

// Problem constants: N=32768 nodes, E=262144 edges, HID=64, HEADS=4
#define HIDDEN 64
#define HEADS 4
#define HC 256   // HEADS * HIDDEN
#define CAP 64   // bucket capacity per dst node (Poisson(8): P(deg>64) ~ 0)

typedef __attribute__((ext_vector_type(8))) short short8;   // 8 bf16 (4 VGPRs)
typedef __attribute__((ext_vector_type(4))) float f32x4;    // MFMA acc

__device__ __forceinline__ unsigned short f2bf(float f) {
    unsigned int u = __float_as_uint(f);
    u += 0x7fffu + ((u >> 16) & 1u);   // round-to-nearest-even
    return (unsigned short)(u >> 16);
}

// ---------------- fused prep + bucket (role-split, no inter-role deps) ------
// [0,1024):     bucket: slot=dst*CAP+atomic count; sb[slot]=src, eab[slot]=ea
// [1024,3072):  zb = bf16(h), 4 floats/thread
// [3072,3136):  wt1/wt2[c*64+k] = bf16(W[k*256+c])  (transposed for tmfma)
// 3136:         wr (We @ att_edge reductions, both layers)
// Requires counts==0 on entry (hipMemsetAsync before launch).
__global__ __launch_bounds__(256) void k_fused(const int* __restrict__ dst,
                                               const int* __restrict__ src,
                                               const float* __restrict__ ea,
                                               const float* __restrict__ h,
                                               const float* __restrict__ W1f,
                                               const float* __restrict__ W2f,
                                               const float* __restrict__ We1,
                                               const float* __restrict__ at1,
                                               const float* __restrict__ We2,
                                               const float* __restrict__ at2,
                                               int* __restrict__ counts,
                                               int* __restrict__ sb,
                                               float* __restrict__ eab,
                                               ushort* __restrict__ zb,
                                               ushort* __restrict__ wt1,
                                               ushort* __restrict__ wt2,
                                               float* __restrict__ wr, int E) {
    int t = threadIdx.x, b = blockIdx.x;
    if (b < 1024) {
        int e = b * 256 + t;
        if (e < E) {
            int d = dst[e];
            int c = atomicAdd(&counts[d], 1);
            if (c < CAP) {   // statistically impossible overflow; safety clamp
                size_t slot = (size_t)d * CAP + c;
                sb[slot] = src[e];
                *(float4*)&eab[slot * 4] =
                    make_float4(ea[e * 3 + 0], ea[e * 3 + 1], ea[e * 3 + 2], 0.f);
            }
        }
    } else if (b < 3072) {
        int i = (b - 1024) * 256 + t;
        float4 v = ((const float4*)h)[i];
        ushort4 o;
        o.x = f2bf(v.x); o.y = f2bf(v.y); o.z = f2bf(v.z); o.w = f2bf(v.w);
        ((ushort4*)zb)[i] = o;
    } else if (b < 3136) {
        int j = (b - 3072) * 256 + t;   // 0..16383
        int c = j >> 6, k = j & 63;
        wt1[j] = f2bf(W1f[k * HC + c]);
        wt2[j] = f2bf(W2f[k * HC + c]);
    } else {
        int wv = t >> 6, lane = t & 63;
#pragma unroll
        for (int it = 0; it < 6; ++it) {
            int comb = wv + it * 4;          // 0..23
            int layer = comb / 12;
            int dh = comb % 12;
            int d = dh >> 2, hh = dh & 3;
            const float* We = layer ? We2 : We1;
            const float* at = layer ? at2 : at1;
            float v = We[d * HC + hh * HIDDEN + lane] * at[hh * HIDDEN + lane];
            for (int o = 32; o > 0; o >>= 1) v += __shfl_down(v, o);
            if (lane == 0) wr[layer * 16 + d * HEADS + hh] = v;
        }
    }
}

// ---------------- MFMA transform (R12-proven) ----------------
// x = z @ W (64 -> 256) via mfma_f32_16x16x32_bf16, fused alpha_src/alpha_dst.
__global__ __launch_bounds__(256) void k_tmfma(const ushort* __restrict__ zb,
                                               const ushort* __restrict__ wt,
                                               const float* __restrict__ asw,
                                               const float* __restrict__ adw,
                                               ushort* __restrict__ xb,
                                               float* __restrict__ as_,
                                               float* __restrict__ ad_) {
    int wave = threadIdx.x >> 6, lane = threadIdx.x & 63;
    int q = lane & 15, quad = lane >> 4;
    int row0 = blockIdx.x * 64 + wave * 16;

    const ushort* zrow = zb + (size_t)(row0 + q) * 64 + quad * 8;
    short8 a0 = *(const short8*)(zrow);
    short8 a1 = *(const short8*)(zrow + 32);

#pragma unroll
    for (int h = 0; h < 4; ++h) {
        float vs[4] = {0.f, 0.f, 0.f, 0.f};
        float vd[4] = {0.f, 0.f, 0.f, 0.f};
#pragma unroll
        for (int nt = 0; nt < 4; ++nt) {
            int col0 = h * 64 + nt * 16;
            const ushort* wrow = wt + (size_t)(col0 + q) * 64 + quad * 8;
            short8 b0 = *(const short8*)(wrow);
            short8 b1 = *(const short8*)(wrow + 32);
            f32x4 acc = {0.f, 0.f, 0.f, 0.f};
            acc = __builtin_amdgcn_mfma_f32_16x16x32_bf16(a0, b0, acc, 0, 0, 0);
            acc = __builtin_amdgcn_mfma_f32_16x16x32_bf16(a1, b1, acc, 0, 0, 0);
            int c = col0 + q;
            float aw = asw[c], dw = adw[c];
#pragma unroll
            for (int r = 0; r < 4; ++r) {
                float v = acc[r];
                xb[(size_t)(row0 + quad * 4 + r) * HC + c] = f2bf(v);
                vs[r] += v * aw;
                vd[r] += v * dw;
            }
        }
#pragma unroll
        for (int o = 1; o < 16; o <<= 1) {
#pragma unroll
            for (int r = 0; r < 4; ++r) {
                vs[r] += __shfl_xor(vs[r], o);
                vd[r] += __shfl_xor(vd[r], o);
            }
        }
        if (q < 4) {
            int n = row0 + quad * 4 + q;
            as_[n * 4 + h] = vs[q];
            ad_[n * 4 + h] = vd[q];
        }
    }
}

// Single-pass aggregate (R12-proven) with inline aes from raw edge_attr + wr.
// Wave per node, grid-stride. lane = h*16 + sub; gather (e,g)=(sub&1,sub>>1).
__global__ __launch_bounds__(256) void k_aggregate(
        const ushort* __restrict__ xb, const float* __restrict__ eab,
        const int* __restrict__ sb, const int* __restrict__ counts,
        const float* __restrict__ as_, const float* __restrict__ ad_,
        const float* __restrict__ wrl,
        const float* __restrict__ bias, const float* __restrict__ lng,
        const float* __restrict__ lnb, float* __restrict__ outf,
        ushort* __restrict__ outb, int N) {
    int lane = threadIdx.x & 63;
    int h = lane >> 4, sub = lane & 15;
    int e = sub & 1, g = sub >> 1;
    int wid = blockIdx.x * 4 + (threadIdx.x >> 6);
    int nwaves = gridDim.x * 4;

    // per-lane wr row for this head (L2-resident 12 floats/layer)
    float w0 = wrl[h], w1 = wrl[4 + h], w2 = wrl[8 + h];

    float bs[8], gm[8], bt[8];
#pragma unroll
    for (int k = 0; k < 8; ++k) {
        bs[k] = bias[g * 8 + k];
        gm[k] = lng[g * 8 + k];
        bt[k] = lnb[g * 8 + k];
    }

    for (int n = wid; n < N; n += nwaves) {
        int deg = counts[n];
        if (deg > CAP) deg = CAP;
        int base = n * CAP;
        float ad4 = ad_[n * 4 + h];

        float ssum = 0.f;
        float acc[8];
#pragma unroll
        for (int k = 0; k < 8; ++k) acc[k] = 0.f;

        for (int cs = 0; cs < deg; cs += 16) {
            int idx = cs + sub;
            int s_sub = 0;
            float wgt = 0.f;
            if (idx < deg) {
                s_sub = sb[base + idx];
                float4 av = *(const float4*)&eab[(size_t)(base + idx) * 4];
                float lg = as_[s_sub * 4 + h] + ad4
                         + av.x * w0 + av.y * w1 + av.z * w2;
                lg = (lg >= 0.f) ? lg : 0.2f * lg;
                wgt = __expf(lg);
            }
            ssum += wgt;

            int jb = deg - cs; if (jb > 16) jb = 16;
            for (int j4 = 0; j4 < jb; j4 += 4) {
                int sl0 = h * 16 + j4 + e;
                int sl1 = h * 16 + j4 + 2 + e;
                float q0 = __shfl(wgt, sl0);
                int s0 = __shfl(s_sub, sl0);
                float q1 = __shfl(wgt, sl1);
                int s1 = __shfl(s_sub, sl1);
                uint4 r0 = *(const uint4*)&xb[(size_t)s0 * HC + h * HIDDEN + g * 8];
                uint4 r1 = *(const uint4*)&xb[(size_t)s1 * HC + h * HIDDEN + g * 8];
                unsigned int u0[4] = {r0.x, r0.y, r0.z, r0.w};
                unsigned int u1[4] = {r1.x, r1.y, r1.z, r1.w};
#pragma unroll
                for (int k = 0; k < 4; ++k) {
                    acc[2 * k + 0] += q0 * __uint_as_float(u0[k] << 16);
                    acc[2 * k + 1] += q0 * __uint_as_float(u0[k] & 0xffff0000u);
                    acc[2 * k + 0] += q1 * __uint_as_float(u1[k] << 16);
                    acc[2 * k + 1] += q1 * __uint_as_float(u1[k] & 0xffff0000u);
                }
            }
        }
        // reduce ssum over the 16 lanes of this head group (once per node)
#pragma unroll
        for (int o = 1; o < 16; o <<= 1) ssum += __shfl_xor(ssum, o);
        float winv = 1.f / (ssum + 1e-16f);
#pragma unroll
        for (int k = 0; k < 8; ++k) acc[k] *= winv;
        // reduce acc over edge slot (bit 0) and heads (bits 4,5)
#pragma unroll
        for (int k = 0; k < 8; ++k) {
            acc[k] += __shfl_xor(acc[k], 1);
            acc[k] += __shfl_xor(acc[k], 16);
            acc[k] += __shfl_xor(acc[k], 32);
        }

        // epilogue: head mean + bias + LayerNorm + SiLU
        float u8[8], s1 = 0.f;
#pragma unroll
        for (int k = 0; k < 8; ++k) {
            u8[k] = acc[k] * 0.25f + bs[k];
            s1 += u8[k];
        }
#pragma unroll
        for (int o = 2; o < 16; o <<= 1) s1 += __shfl_xor(s1, o);
        float mu = s1 * (1.f / 64.f);
        float s2 = 0.f;
#pragma unroll
        for (int k = 0; k < 8; ++k) {
            float d = u8[k] - mu;
            s2 += d * d;
        }
#pragma unroll
        for (int o = 2; o < 16; o <<= 1) s2 += __shfl_xor(s2, o);
        float rstd = rsqrtf(s2 * (1.f / 64.f) + 1e-5f);
        float r[8];
#pragma unroll
        for (int k = 0; k < 8; ++k) {
            float y = (u8[k] - mu) * rstd * gm[k] + bt[k];
            r[k] = y / (1.f + __expf(-y));
        }
        if ((lane & 49) == 0) {   // h==0 && e==0: 8 lanes, one per g
            if (outb) {
                uint4 pk;
                pk.x = (unsigned)f2bf(r[0]) | ((unsigned)f2bf(r[1]) << 16);
                pk.y = (unsigned)f2bf(r[2]) | ((unsigned)f2bf(r[3]) << 16);
                pk.z = (unsigned)f2bf(r[4]) | ((unsigned)f2bf(r[5]) << 16);
                pk.w = (unsigned)f2bf(r[6]) | ((unsigned)f2bf(r[7]) << 16);
                *(uint4*)&outb[(size_t)n * HIDDEN + g * 8] = pk;
            } else {
                float4* o4 = (float4*)&outf[(size_t)n * HIDDEN + g * 8];
                o4[0] = make_float4(r[0], r[1], r[2], r[3]);
                o4[1] = make_float4(r[4], r[5], r[6], r[7]);
            }
        }
    }
}

// ---------------- launch ----------------

extern "C" void kernel_launch(void* const* d_in, const int* in_sizes, int n_in,
                              void* d_out, int out_size, void* d_ws, size_t ws_size,
                              hipStream_t stream) {
    const float* h   = (const float*)d_in[1];
    const int*   ei  = (const int*)d_in[2];
    const float* ea  = (const float*)d_in[3];
    const float* W1  = (const float*)d_in[4];
    const float* We1 = (const float*)d_in[5];
    const float* as1 = (const float*)d_in[6];
    const float* ad1 = (const float*)d_in[7];
    const float* ae1 = (const float*)d_in[8];
    const float* b1  = (const float*)d_in[9];
    const float* lg1 = (const float*)d_in[10];
    const float* lb1 = (const float*)d_in[11];
    const float* W2  = (const float*)d_in[12];
    const float* We2 = (const float*)d_in[13];
    const float* as2 = (const float*)d_in[14];
    const float* ad2 = (const float*)d_in[15];
    const float* ae2 = (const float*)d_in[16];
    const float* b2  = (const float*)d_in[17];
    const float* lg2 = (const float*)d_in[18];
    const float* lb2 = (const float*)d_in[19];

    const int N = in_sizes[1] / HIDDEN;   // 32768
    const int E = in_sizes[2] / 2;        // 262144
    const int* srcp = ei;
    const int* dstp = ei + E;

    // workspace layout (all regions fully written before read)
    char* w = (char*)d_ws;
    ushort* xb    = (ushort*)w; w += (size_t)N * HC * 2;        // 16.75 MB
    ushort* zb    = (ushort*)w; w += (size_t)N * HIDDEN * 2;    // 4 MB
    float* as_    = (float*)w;  w += (size_t)N * HEADS * 4;
    float* adv    = (float*)w;  w += (size_t)N * HEADS * 4;
    ushort* wt1   = (ushort*)w; w += 16384 * 2;
    ushort* wt2   = (ushort*)w; w += 16384 * 2;
    float* wr     = (float*)w;  w += 128;
    int* counts   = (int*)w;    w += (size_t)N * 4;
    int* sb       = (int*)w;    w += (size_t)N * CAP * 4;       // 8 MB
    float* eab    = (float*)w;  w += (size_t)N * CAP * 4 * 4;   // 32 MB

    // zero counts (memset node in the graph), then fused prep || bucket
    hipMemsetAsync(counts, 0, (size_t)N * 4, stream);
    k_fused<<<3137, 256, 0, stream>>>(dstp, srcp, ea, h, W1, W2,
                                      We1, ae1, We2, ae2,
                                      counts, sb, eab, zb, wt1, wt2, wr, E);

    // layer 1
    k_tmfma<<<N / 64, 256, 0, stream>>>(zb, wt1, as1, ad1, xb, as_, adv);
    k_aggregate<<<4096, 256, 0, stream>>>(xb, eab, sb, counts, as_, adv, wr,
                                          b1, lg1, lb1, nullptr, zb, N);
    // layer 2 (reads zb written by layer-1 aggregate)
    k_tmfma<<<N / 64, 256, 0, stream>>>(zb, wt2, as2, ad2, xb, as_, adv);
    k_aggregate<<<4096, 256, 0, stream>>>(xb, eab, sb, counts, as_, adv, wr + 16,
                                          b2, lg2, lb2, (float*)d_out, nullptr, N);
}